// Round 2
// baseline (4841.330 us; speedup 1.0000x reference)
//
#include <hip/hip_runtime.h>
#include <hip/hip_bf16.h>

#define R_ 64
#define I_ 512
#define N_ 4
#define E_ 256
#define H_ 8
#define D_ 32
#define RD_ 2048   // R_*D_
typedef unsigned short u16;
typedef unsigned int u32;

__device__ __forceinline__ float bf2f(u16 u) {
  u32 v = ((u32)u) << 16;
  return __builtin_bit_cast(float, v);
}
__device__ __forceinline__ u16 f2bf(float f) {
  u32 i = __builtin_bit_cast(u32, f);
  i += 0x7fffu + ((i >> 16) & 1u);
  return (u16)(i >> 16);
}

// ---------------- K1: q/k/v projection -------------------------------------
// x: (R,I,N,E) f32, rows m=(r*I+i)*N+n. Block: 16 rows, thread = feature f.
// Writes qt/kt/vt bf16 in [n][h][i][r*32+d] layout.
__global__ __launch_bounds__(256) void k_proj(
    const float* __restrict__ x,
    const float* __restrict__ Wq, const float* __restrict__ bq,
    const float* __restrict__ Wk, const float* __restrict__ bk,
    const float* __restrict__ Wv, const float* __restrict__ bv,
    u16* __restrict__ qt, u16* __restrict__ kt, u16* __restrict__ vt,
    float scaling)
{
  __shared__ float xs[16][E_];
  const int t = threadIdx.x;
  const int m0 = blockIdx.x * 16;
  #pragma unroll
  for (int g = 0; g < 16; ++g)
    xs[g][t] = x[(size_t)(m0 + g) * E_ + t];
  __syncthreads();

  const int f = t;
  float aq[16], ak[16], av[16];
  #pragma unroll
  for (int g = 0; g < 16; ++g) { aq[g] = 0.f; ak[g] = 0.f; av[g] = 0.f; }

  const float4* wq = (const float4*)(Wq + (size_t)f * E_);
  const float4* wk = (const float4*)(Wk + (size_t)f * E_);
  const float4* wv = (const float4*)(Wv + (size_t)f * E_);

  for (int e0 = 0; e0 < E_/4; ++e0) {
    float4 A = wq[e0], B = wk[e0], C = wv[e0];
    #pragma unroll
    for (int g = 0; g < 16; ++g) {
      const float* xr = &xs[g][e0*4];
      float x0=xr[0],x1=xr[1],x2=xr[2],x3=xr[3];
      aq[g] = fmaf(x3,A.w, fmaf(x2,A.z, fmaf(x1,A.y, fmaf(x0,A.x, aq[g]))));
      ak[g] = fmaf(x3,B.w, fmaf(x2,B.z, fmaf(x1,B.y, fmaf(x0,B.x, ak[g]))));
      av[g] = fmaf(x3,C.w, fmaf(x2,C.z, fmaf(x1,C.y, fmaf(x0,C.x, av[g]))));
    }
  }

  const int h = f >> 5, d = f & 31;
  const float bqf = bq[f], bkf = bk[f], bvf = bv[f];
  #pragma unroll
  for (int g = 0; g < 16; ++g) {
    int m = m0 + g;
    int n = m & (N_-1);
    int ri = m >> 2;
    int i = ri & (I_-1);
    int r = ri >> 9;
    size_t o = ((size_t)((n*H_ + h)*I_ + i)) * RD_ + r*D_ + d;
    qt[o] = f2bf((aq[g] + bqf) * scaling);
    kt[o] = f2bf(ak[g] + bkf);
    vt[o] = f2bf(av[g] + bvf);
  }
}

// ---------------- K2: logits + rel-pos bias + softmax ----------------------
// Block = (n, h, i-tile of 8). Thread t owns columns j=t and j=t+256.
// probs written f32 straight into d_out's second region, layout (H,N,I,J).
__global__ __launch_bounds__(256) void k_attn(
    const u16* __restrict__ qt, const u16* __restrict__ kt,
    const int* __restrict__ dist, const float* __restrict__ rel,
    float* __restrict__ probs)
{
  __shared__ u16 qs[8][RD_];     // 32 KB
  __shared__ float ls[8][I_];    // 16 KB
  __shared__ float wred[8];
  const int t = threadIdx.x;
  const int b = blockIdx.x;
  const int it = b & 63, h = (b >> 6) & 7, n = b >> 9;
  const int i0 = it * 8;

  { // q tile: one contiguous 32 KB chunk
    const uint4* src = (const uint4*)(qt + ((size_t)((n*H_ + h)*I_ + i0)) * RD_);
    uint4* dst = (uint4*)(&qs[0][0]);
    for (int k = t; k < 8*RD_/8; k += 256) dst[k] = src[k];
  }
  __syncthreads();

  const int j1 = t, j2 = t + 256;
  float acc[8][2];
  #pragma unroll
  for (int g = 0; g < 8; ++g) { acc[g][0] = 0.f; acc[g][1] = 0.f; }
  const ushort4* ka = (const ushort4*)(kt + ((size_t)((n*H_ + h)*I_ + j1)) * RD_);
  const ushort4* kb = (const ushort4*)(kt + ((size_t)((n*H_ + h)*I_ + j2)) * RD_);

  for (int e0 = 0; e0 < RD_/4; ++e0) {
    ushort4 A = ka[e0], B = kb[e0];
    float a0=bf2f(A.x),a1=bf2f(A.y),a2=bf2f(A.z),a3=bf2f(A.w);
    float b0=bf2f(B.x),b1=bf2f(B.y),b2=bf2f(B.z),b3=bf2f(B.w);
    #pragma unroll
    for (int g = 0; g < 8; ++g) {
      ushort4 Q = ((const ushort4*)&qs[g][0])[e0];   // wave-uniform -> broadcast
      float q0=bf2f(Q.x),q1=bf2f(Q.y),q2=bf2f(Q.z),q3=bf2f(Q.w);
      acc[g][0] = fmaf(q3,a3, fmaf(q2,a2, fmaf(q1,a1, fmaf(q0,a0, acc[g][0]))));
      acc[g][1] = fmaf(q3,b3, fmaf(q2,b2, fmaf(q1,b1, fmaf(q0,b0, acc[g][1]))));
    }
  }

  // add T5-style bias (exact integer bucketize), store logits
  #pragma unroll
  for (int g = 0; g < 8; ++g) {
    const int i = i0 + g;
    int d1 = dist[((size_t)n*I_ + i)*I_ + j1];
    int d2 = dist[((size_t)n*I_ + i)*I_ + j2];
    d1 = d1 < 0 ? -d1 : d1;  d2 = d2 < 0 ? -d2 : d2;
    int u1 = (62*d1 + 49999) / 50000; if (u1 > 63) u1 = 63;
    int u2 = (62*d2 + 49999) / 50000; if (u2 > 63) u2 = 63;
    ls[g][j1] = acc[g][0] + rel[u1*H_ + h];
    ls[g][j2] = acc[g][1] + rel[u2*H_ + h];
  }
  __syncthreads();

  // softmax over j (512) per row, write probs f32
  for (int g = 0; g < 8; ++g) {
    float v1 = ls[g][t], v2 = ls[g][t + 256];
    float m = fmaxf(v1, v2);
    #pragma unroll
    for (int off = 32; off; off >>= 1) m = fmaxf(m, __shfl_xor(m, off));
    if ((t & 63) == 0) wred[t >> 6] = m;
    __syncthreads();
    m = fmaxf(fmaxf(wred[0], wred[1]), fmaxf(wred[2], wred[3]));
    float e1 = __expf(v1 - m), e2 = __expf(v2 - m);
    float s = e1 + e2;
    #pragma unroll
    for (int off = 32; off; off >>= 1) s += __shfl_xor(s, off);
    if ((t & 63) == 0) wred[4 + (t >> 6)] = s;
    __syncthreads();
    s = (wred[4] + wred[5]) + (wred[6] + wred[7]);
    float inv = 1.0f / s;
    size_t o = ((size_t)((h*N_ + n)*I_ + i0 + g)) * I_;
    probs[o + t]       = e1 * inv;
    probs[o + t + 256] = e2 * inv;
    __syncthreads();
  }
}

// ---------------- K3: context = P @ V --------------------------------------
// Block = (n, h, i-tile 8, col-half). Thread owns 4 consecutive cols of RD.
// Writes ct f32 in x-layout (R,I,N,E).
__global__ __launch_bounds__(256) void k_ctx(
    const float* __restrict__ probs, const u16* __restrict__ vt,
    float* __restrict__ ct)
{
  __shared__ float ps[8][I_];   // 16 KB
  const int t = threadIdx.x;
  const int b = blockIdx.x;
  const int c2 = b & 1, it = (b >> 1) & 63, h = (b >> 7) & 7, n = b >> 10;
  const int i0 = it * 8;

  for (int k = t; k < 8 * I_; k += 256) {
    int g = k >> 9, j = k & (I_-1);
    ps[g][j] = probs[((size_t)((h*N_ + n)*I_ + i0 + g)) * I_ + j];
  }
  __syncthreads();

  const int c = c2 * 1024 + t * 4;
  float acc[8][4];
  #pragma unroll
  for (int g = 0; g < 8; ++g) { acc[g][0]=0.f; acc[g][1]=0.f; acc[g][2]=0.f; acc[g][3]=0.f; }

  const ushort4* vp = (const ushort4*)(vt + ((size_t)((n*H_ + h)*I_)) * RD_ + c);
  for (int j = 0; j < I_; ++j) {
    ushort4 V = vp[(size_t)j * (RD_/4)];
    float v0=bf2f(V.x),v1=bf2f(V.y),v2=bf2f(V.z),v3=bf2f(V.w);
    #pragma unroll
    for (int g = 0; g < 8; ++g) {
      float p = ps[g][j];   // wave-uniform -> broadcast
      acc[g][0] = fmaf(p, v0, acc[g][0]);
      acc[g][1] = fmaf(p, v1, acc[g][1]);
      acc[g][2] = fmaf(p, v2, acc[g][2]);
      acc[g][3] = fmaf(p, v3, acc[g][3]);
    }
  }

  const int r = c >> 5, d = c & 31;
  #pragma unroll
  for (int g = 0; g < 8; ++g) {
    int i = i0 + g;
    size_t o = ((size_t)(r*I_ + i)*N_ + n) * E_ + h*D_ + d;
    float4 w;
    w.x = acc[g][0]; w.y = acc[g][1]; w.z = acc[g][2]; w.w = acc[g][3];
    *(float4*)(ct + o) = w;
  }
}

// ---------------- K4: output projection ------------------------------------
__global__ __launch_bounds__(256) void k_oproj(
    const float* __restrict__ ct, const float* __restrict__ Wo,
    const float* __restrict__ bo, float* __restrict__ out)
{
  __shared__ float cs[16][E_];
  const int t = threadIdx.x;
  const int m0 = blockIdx.x * 16;
  #pragma unroll
  for (int g = 0; g < 16; ++g)
    cs[g][t] = ct[(size_t)(m0 + g) * E_ + t];
  __syncthreads();

  float acc[16];
  #pragma unroll
  for (int g = 0; g < 16; ++g) acc[g] = 0.f;

  const float4* wp = (const float4*)(Wo + (size_t)t * E_);
  for (int e0 = 0; e0 < E_/4; ++e0) {
    float4 W = wp[e0];
    #pragma unroll
    for (int g = 0; g < 16; ++g) {
      const float* xr = &cs[g][e0*4];
      acc[g] = fmaf(xr[3],W.w, fmaf(xr[2],W.z, fmaf(xr[1],W.y, fmaf(xr[0],W.x, acc[g]))));
    }
  }
  const float bf = bo[t];
  #pragma unroll
  for (int g = 0; g < 16; ++g)
    out[(size_t)(m0 + g) * E_ + t] = acc[g] + bf;
}

extern "C" void kernel_launch(void* const* d_in, const int* in_sizes, int n_in,
                              void* d_out, int out_size, void* d_ws, size_t ws_size,
                              hipStream_t stream) {
  const float* x  = (const float*)d_in[0];
  const int* dist = (const int*)d_in[1];
  const float* Wq = (const float*)d_in[2];
  const float* bq = (const float*)d_in[3];
  const float* Wk = (const float*)d_in[4];
  const float* bk = (const float*)d_in[5];
  const float* Wv = (const float*)d_in[6];
  const float* bv = (const float*)d_in[7];
  const float* Wo = (const float*)d_in[8];
  const float* bo = (const float*)d_in[9];
  const float* rel = (const float*)d_in[10];
  float* out = (float*)d_out;

  const size_t QKV = (size_t)N_ * H_ * I_ * RD_;   // 33,554,432 elements
  u16* qt = (u16*)d_ws;
  u16* kt = qt + QKV;
  u16* vt = kt + QKV;
  float* ct = (float*)d_ws;                        // alias qt+kt (both dead after K2/K3 start)
  float* probs = out + (size_t)R_ * I_ * N_ * E_;  // second output region (H,N,I,J)

  const float scaling = 0.022097086912079608f;     // 32^-0.5 / sqrt(64)

  k_proj <<<dim3(8192), dim3(256), 0, stream>>>(x, Wq, bq, Wk, bk, Wv, bv, qt, kt, vt, scaling);
  k_attn <<<dim3(2048), dim3(256), 0, stream>>>(qt, kt, dist, rel, probs);
  k_ctx  <<<dim3(4096), dim3(256), 0, stream>>>(probs, vt, ct);
  k_oproj<<<dim3(8192), dim3(256), 0, stream>>>(ct, Wo, bo, out);
}

// Round 3
// 391.617 us; speedup vs baseline: 12.3624x; 12.3624x over previous
//
#include <hip/hip_runtime.h>

typedef unsigned short u16;
typedef unsigned int u32;
typedef float f32x4 __attribute__((ext_vector_type(4)));
typedef short bf16x8 __attribute__((ext_vector_type(8)));
typedef unsigned short u16x8 __attribute__((ext_vector_type(8)));

#define SL 33554432u   // one 67MB slot, in u16 elements

__device__ __forceinline__ float bf2f(u16 u) {
  u32 v = ((u32)u) << 16;
  return __builtin_bit_cast(float, v);
}
__device__ __forceinline__ u16 f2bf(float f) {
  u32 i = __builtin_bit_cast(u32, f);
  i += 0x7fffu + ((i >> 16) & 1u);
  return (u16)(i >> 16);
}

#define GLDS16(g, l) __builtin_amdgcn_global_load_lds( \
    (const __attribute__((address_space(1))) void*)(g), \
    (__attribute__((address_space(3))) void*)(l), 16, 0, 0)

// ---- shared GEMM core: 128x128 tile, BK=64, 4 waves (2x2), bf16 MFMA ------
// A,B row-major with contiguous K (B^T form): C[m][n] = sum_k A[m][k]*B[n][k]
// LDS swizzle: logical (row, c16) at byte row*128 + ((c16 ^ (row&7))*16).
__device__ __forceinline__ void stage128(const u16* gbase, int ldk, u16* lds, int tid) {
  #pragma unroll
  for (int rep = 0; rep < 4; ++rep) {
    int c = tid + rep * 256;            // chunk 0..1023
    int row = c >> 3, slot = c & 7;
    const u16* g = gbase + (size_t)row * ldk + ((slot ^ (row & 7)) << 3);
    GLDS16(g, lds + c * 8);
  }
}

__device__ __forceinline__ void mfma128(const u16* As, const u16* Bs, int lane,
                                        int wm0, int wn0, f32x4 acc[4][4]) {
  #pragma unroll
  for (int kk = 0; kk < 2; ++kk) {
    bf16x8 a[4], b[4];
    #pragma unroll
    for (int mi = 0; mi < 4; ++mi) {
      int r = wm0 + mi * 16 + (lane & 15);
      int c16 = (kk * 4 + (lane >> 4)) ^ (r & 7);
      a[mi] = *(const bf16x8*)(As + r * 64 + c16 * 8);
    }
    #pragma unroll
    for (int ni = 0; ni < 4; ++ni) {
      int r = wn0 + ni * 16 + (lane & 15);
      int c16 = (kk * 4 + (lane >> 4)) ^ (r & 7);
      b[ni] = *(const bf16x8*)(Bs + r * 64 + c16 * 8);
    }
    #pragma unroll
    for (int mi = 0; mi < 4; ++mi)
      #pragma unroll
      for (int ni = 0; ni < 4; ++ni)
        acc[mi][ni] = __builtin_amdgcn_mfma_f32_16x16x32_bf16(a[mi], b[ni], acc[mi][ni], 0, 0, 0);
  }
}

__device__ __forceinline__ void gemm_core(const u16* A, int ldkA, const u16* B, int ldkB,
                                          int NT, u16* As, u16* Bs,
                                          int tid, int lane, int wm0, int wn0,
                                          f32x4 acc[4][4]) {
  for (int t = 0; t < NT; ++t) {
    stage128(A + t * 64, ldkA, As, tid);
    stage128(B + t * 64, ldkB, Bs, tid);
    __syncthreads();                       // drains vmcnt(0) -> tile resident
    mfma128(As, Bs, lane, wm0, wn0, acc);
    __syncthreads();                       // protect LDS reuse
  }
}

// ---------------- cast f32 -> bf16 (x and weights) -------------------------
__global__ __launch_bounds__(256) void k_cast(const float* __restrict__ src,
                                              u16* __restrict__ dst, int n8) {
  int idx = blockIdx.x * 256 + threadIdx.x;
  if (idx >= n8) return;
  const float4* s = (const float4*)src;
  float4 a = s[(size_t)idx * 2], b = s[(size_t)idx * 2 + 1];
  u16x8 o;
  o[0] = f2bf(a.x); o[1] = f2bf(a.y); o[2] = f2bf(a.z); o[3] = f2bf(a.w);
  o[4] = f2bf(b.x); o[5] = f2bf(b.y); o[6] = f2bf(b.z); o[7] = f2bf(b.w);
  *(u16x8*)(dst + (size_t)idx * 8) = o;
}

// ---------------- K1: fused q/k/v projection GEMM --------------------------
// grid (1024 mtiles, 2 ntiles, 3 wsel). A = xb [131072][256], B = W [256][256].
__global__ __launch_bounds__(256) void k_proj_mm(
    const u16* __restrict__ xb, const u16* __restrict__ Wb,
    const float* __restrict__ bq, const float* __restrict__ bk, const float* __restrict__ bv,
    u16* __restrict__ qt, u16* __restrict__ kt, u16* __restrict__ vt, float scaling) {
  __shared__ __align__(16) u16 As[128 * 64];
  __shared__ __align__(16) u16 Bs[128 * 64];
  const int tid = threadIdx.x, lane = tid & 63, wave = tid >> 6;
  const int wm0 = (wave >> 1) * 64, wn0 = (wave & 1) * 64;
  const int w = blockIdx.z;
  const int m0 = blockIdx.x * 128, n0 = blockIdx.y * 128;

  f32x4 acc[4][4];
  #pragma unroll
  for (int mi = 0; mi < 4; ++mi)
    #pragma unroll
    for (int ni = 0; ni < 4; ++ni) acc[mi][ni] = (f32x4){0.f, 0.f, 0.f, 0.f};

  gemm_core(xb + (size_t)m0 * 256, 256, Wb + w * 65536 + (size_t)n0 * 256, 256,
            4, As, Bs, tid, lane, wm0, wn0, acc);

  const float* bias = (w == 0) ? bq : (w == 1) ? bk : bv;
  u16* dst = (w == 0) ? qt : (w == 1) ? kt : vt;
  const float sc = (w == 0) ? scaling : 1.0f;

  #pragma unroll
  for (int mi = 0; mi < 4; ++mi)
    #pragma unroll
    for (int ni = 0; ni < 4; ++ni) {
      int f = n0 + wn0 + ni * 16 + (lane & 15);
      int h = f >> 5, d = f & 31;
      float bb = bias[f];
      #pragma unroll
      for (int q = 0; q < 4; ++q) {
        int m = m0 + wm0 + mi * 16 + (lane >> 4) * 4 + q;
        int n = m & 3, i = (m >> 2) & 511, r = m >> 11;
        size_t o = ((size_t)((n * 8 + h) * 512 + i)) * 2048 + r * 32 + d;
        dst[o] = f2bf((acc[mi][ni][q] + bb) * sc);
      }
    }
}

// ---------------- K2a: attention logits GEMM -------------------------------
// grid (16, 32): per nh, Q[512][2048] x K^T -> lgt bf16 [nh][i][j]
__global__ __launch_bounds__(256) void k_attn_mm(
    const u16* __restrict__ qt, const u16* __restrict__ kt, u16* __restrict__ lgt) {
  __shared__ __align__(16) u16 As[128 * 64];
  __shared__ __align__(16) u16 Bs[128 * 64];
  const int tid = threadIdx.x, lane = tid & 63, wave = tid >> 6;
  const int wm0 = (wave >> 1) * 64, wn0 = (wave & 1) * 64;
  const int nh = blockIdx.y;
  const int m0 = (blockIdx.x >> 2) * 128, n0 = (blockIdx.x & 3) * 128;

  f32x4 acc[4][4];
  #pragma unroll
  for (int mi = 0; mi < 4; ++mi)
    #pragma unroll
    for (int ni = 0; ni < 4; ++ni) acc[mi][ni] = (f32x4){0.f, 0.f, 0.f, 0.f};

  const size_t base = (size_t)nh * 512 * 2048;
  gemm_core(qt + base + (size_t)m0 * 2048, 2048, kt + base + (size_t)n0 * 2048, 2048,
            32, As, Bs, tid, lane, wm0, wn0, acc);

  #pragma unroll
  for (int mi = 0; mi < 4; ++mi)
    #pragma unroll
    for (int ni = 0; ni < 4; ++ni) {
      int col = n0 + wn0 + ni * 16 + (lane & 15);
      #pragma unroll
      for (int q = 0; q < 4; ++q) {
        int row = m0 + wm0 + mi * 16 + (lane >> 4) * 4 + q;
        lgt[(size_t)nh * 262144 + (size_t)row * 512 + col] = f2bf(acc[mi][ni][q]);
      }
    }
}

// ---------------- K2b: bias + softmax --------------------------------------
// Block (n,h,itile8). Reads lgt bf16, writes probs f32 (H,N,I,J) + pbf bf16 [nh][i][j].
__global__ __launch_bounds__(256) void k_softmax(
    const u16* __restrict__ lgt, const int* __restrict__ dist, const float* __restrict__ rel,
    float* __restrict__ probs, u16* __restrict__ pbf) {
  __shared__ float wred[8];
  const int t = threadIdx.x;
  const int b = blockIdx.x;
  const int it = b & 63, h = (b >> 6) & 7, n = b >> 9;
  const int i0 = it * 8, nh = n * 8 + h;

  for (int g = 0; g < 8; ++g) {
    const int i = i0 + g;
    const size_t lrow = ((size_t)nh * 512 + i) * 512;
    float v1 = bf2f(lgt[lrow + t]);
    float v2 = bf2f(lgt[lrow + t + 256]);
    int d1 = dist[((size_t)n * 512 + i) * 512 + t];
    int d2 = dist[((size_t)n * 512 + i) * 512 + t + 256];
    d1 = d1 < 0 ? -d1 : d1;  d2 = d2 < 0 ? -d2 : d2;
    int u1 = (62 * d1 + 49999) / 50000; if (u1 > 63) u1 = 63;
    int u2 = (62 * d2 + 49999) / 50000; if (u2 > 63) u2 = 63;
    v1 += rel[u1 * 8 + h];
    v2 += rel[u2 * 8 + h];

    float m = fmaxf(v1, v2);
    #pragma unroll
    for (int off = 32; off; off >>= 1) m = fmaxf(m, __shfl_xor(m, off));
    if ((t & 63) == 0) wred[t >> 6] = m;
    __syncthreads();
    m = fmaxf(fmaxf(wred[0], wred[1]), fmaxf(wred[2], wred[3]));
    float e1 = __expf(v1 - m), e2 = __expf(v2 - m);
    float s = e1 + e2;
    #pragma unroll
    for (int off = 32; off; off >>= 1) s += __shfl_xor(s, off);
    if ((t & 63) == 0) wred[4 + (t >> 6)] = s;
    __syncthreads();
    s = (wred[4] + wred[5]) + (wred[6] + wred[7]);
    float inv = 1.0f / s;
    float p1 = e1 * inv, p2 = e2 * inv;
    size_t po = ((size_t)(h * 4 + n) * 512 + i) * 512;
    probs[po + t] = p1;
    probs[po + t + 256] = p2;
    size_t pb = ((size_t)nh * 512 + i) * 512;
    pbf[pb + t] = f2bf(p1);
    pbf[pb + t + 256] = f2bf(p2);
    __syncthreads();
  }
}

// ---------------- V transpose: vt [nh][i][c] -> vtt [nh][c][i] -------------
__global__ __launch_bounds__(256) void k_vtrans(const u16* __restrict__ vt, u16* __restrict__ vtt) {
  __shared__ u16 ts[64][72];
  const int b = blockIdx.x;             // nh*256 + it*32 + ct
  const int ct_ = b & 31, it = (b >> 5) & 7, nh = b >> 8;
  const int i0 = it * 64, c0 = ct_ * 64;
  const int t = threadIdx.x;
  #pragma unroll
  for (int rep = 0; rep < 2; ++rep) {
    int c = t + rep * 256;
    int r = c >> 3, q = c & 7;
    u16x8 v = *(const u16x8*)(vt + ((size_t)nh * 512 + i0 + r) * 2048 + c0 + q * 8);
    #pragma unroll
    for (int j = 0; j < 8; ++j) ts[r][q * 8 + j] = v[j];
  }
  __syncthreads();
  #pragma unroll
  for (int rep = 0; rep < 2; ++rep) {
    int c = t + rep * 256;
    int rr = c >> 3, q = c & 7;
    u16x8 o;
    #pragma unroll
    for (int j = 0; j < 8; ++j) o[j] = ts[q * 8 + j][rr];
    *(u16x8*)(vtt + ((size_t)nh * 2048 + c0 + rr) * 512 + i0 + q * 8) = o;
  }
}

// ---------------- K3: context^T GEMM ---------------------------------------
// grid (64, 32): per nh, A = vtt [2048][512], B = pbf [512][512] -> ctT [nh][c][i] bf16
__global__ __launch_bounds__(256) void k_ctx_mm(
    const u16* __restrict__ vtt, const u16* __restrict__ pbf, u16* __restrict__ ctT) {
  __shared__ __align__(16) u16 As[128 * 64];
  __shared__ __align__(16) u16 Bs[128 * 64];
  const int tid = threadIdx.x, lane = tid & 63, wave = tid >> 6;
  const int wm0 = (wave >> 1) * 64, wn0 = (wave & 1) * 64;
  const int nh = blockIdx.y;
  const int m0 = (blockIdx.x >> 2) * 128, n0 = (blockIdx.x & 3) * 128;

  f32x4 acc[4][4];
  #pragma unroll
  for (int mi = 0; mi < 4; ++mi)
    #pragma unroll
    for (int ni = 0; ni < 4; ++ni) acc[mi][ni] = (f32x4){0.f, 0.f, 0.f, 0.f};

  gemm_core(vtt + (size_t)nh * 1048576 + (size_t)m0 * 512, 512,
            pbf + (size_t)nh * 262144 + (size_t)n0 * 512, 512,
            8, As, Bs, tid, lane, wm0, wn0, acc);

  #pragma unroll
  for (int mi = 0; mi < 4; ++mi)
    #pragma unroll
    for (int ni = 0; ni < 4; ++ni) {
      int col = n0 + wn0 + ni * 16 + (lane & 15);
      #pragma unroll
      for (int q = 0; q < 4; ++q) {
        int row = m0 + wm0 + mi * 16 + (lane >> 4) * 4 + q;
        ctT[(size_t)nh * 1048576 + (size_t)row * 512 + col] = f2bf(acc[mi][ni][q]);
      }
    }
}

// ---------------- ctx^T -> ct (x-layout) transpose -------------------------
// block per (nh, r): ctT [nh][r*32+d][i] -> ct [(r*512+i)*4+n][h*32+d]
__global__ __launch_bounds__(256) void k_ctrans(const u16* __restrict__ ctT, u16* __restrict__ ct) {
  __shared__ u16 ts[32][520];
  const int b = blockIdx.x;             // nh*64 + r
  const int r = b & 63, nh = b >> 6;
  const int n = nh >> 3, h = nh & 7;
  const int t = threadIdx.x;
  #pragma unroll
  for (int rep = 0; rep < 8; ++rep) {
    int c = t + rep * 256;              // 2048 chunks: d(32) x 64
    int d = c >> 6, q = c & 63;
    u16x8 v = *(const u16x8*)(ctT + ((size_t)nh * 2048 + r * 32 + d) * 512 + q * 8);
    #pragma unroll
    for (int j = 0; j < 8; ++j) ts[d][q * 8 + j] = v[j];
  }
  __syncthreads();
  #pragma unroll
  for (int rep = 0; rep < 8; ++rep) {
    int c = t + rep * 256;              // 2048 chunks: i(512) x 4
    int i = c >> 2, q = c & 3;
    u16x8 o;
    #pragma unroll
    for (int j = 0; j < 8; ++j) o[j] = ts[q * 8 + j][i];
    *(u16x8*)(ct + ((size_t)((r * 512 + i) * 4 + n)) * 256 + h * 32 + q * 8) = o;
  }
}

// ---------------- K4: output projection GEMM -------------------------------
// grid (2048): A = ct [131072][256], B = Wo [256][256] -> out f32
__global__ __launch_bounds__(256) void k_oproj_mm(
    const u16* __restrict__ ct, const u16* __restrict__ Wob,
    const float* __restrict__ bo, float* __restrict__ out) {
  __shared__ __align__(16) u16 As[128 * 64];
  __shared__ __align__(16) u16 Bs[128 * 64];
  const int tid = threadIdx.x, lane = tid & 63, wave = tid >> 6;
  const int wm0 = (wave >> 1) * 64, wn0 = (wave & 1) * 64;
  const int m0 = (blockIdx.x >> 1) * 128, n0 = (blockIdx.x & 1) * 128;

  f32x4 acc[4][4];
  #pragma unroll
  for (int mi = 0; mi < 4; ++mi)
    #pragma unroll
    for (int ni = 0; ni < 4; ++ni) acc[mi][ni] = (f32x4){0.f, 0.f, 0.f, 0.f};

  gemm_core(ct + (size_t)m0 * 256, 256, Wob + (size_t)n0 * 256, 256,
            4, As, Bs, tid, lane, wm0, wn0, acc);

  #pragma unroll
  for (int mi = 0; mi < 4; ++mi)
    #pragma unroll
    for (int ni = 0; ni < 4; ++ni) {
      int col = n0 + wn0 + ni * 16 + (lane & 15);
      float bb = bo[col];
      #pragma unroll
      for (int q = 0; q < 4; ++q) {
        int row = m0 + wm0 + mi * 16 + (lane >> 4) * 4 + q;
        out[(size_t)row * 256 + col] = acc[mi][ni][q] + bb;
      }
    }
}

extern "C" void kernel_launch(void* const* d_in, const int* in_sizes, int n_in,
                              void* d_out, int out_size, void* d_ws, size_t ws_size,
                              hipStream_t stream) {
  const float* x  = (const float*)d_in[0];
  const int* dist = (const int*)d_in[1];
  const float* Wq = (const float*)d_in[2];
  const float* bq = (const float*)d_in[3];
  const float* Wk = (const float*)d_in[4];
  const float* bk = (const float*)d_in[5];
  const float* Wv = (const float*)d_in[6];
  const float* bv = (const float*)d_in[7];
  const float* Wo = (const float*)d_in[8];
  const float* bo = (const float*)d_in[9];
  const float* rel = (const float*)d_in[10];
  float* out = (float*)d_out;
  float* probs = out + (size_t)SL;        // second output region (H,N,I,J) f32

  u16* ws = (u16*)d_ws;
  // slot lifetimes: 0: xb -> lgt -> ct ; 1: qt -> pbf ; 2: kt -> vtt ; 3: vt -> ctT
  u16* xb  = ws;
  u16* qt  = ws + (size_t)SL;
  u16* kt  = ws + (size_t)2 * SL;
  u16* vt  = ws + (size_t)3 * SL;
  u16* lgt = xb;
  u16* pbf = qt;
  u16* vtt = kt;
  u16* ctT = vt;
  u16* ctb = xb;
  u16* Wb  = ws + (size_t)4 * SL;         // 4 x 65536 bf16 weights

  const float scaling = 0.022097086912079608f;   // 32^-0.5 / sqrt(64)

  k_cast<<<16384, 256, 0, stream>>>(x, xb, 4194304);
  k_cast<<<32, 256, 0, stream>>>(Wq, Wb, 8192);
  k_cast<<<32, 256, 0, stream>>>(Wk, Wb + 65536, 8192);
  k_cast<<<32, 256, 0, stream>>>(Wv, Wb + 131072, 8192);
  k_cast<<<32, 256, 0, stream>>>(Wo, Wb + 196608, 8192);

  k_proj_mm<<<dim3(1024, 2, 3), 256, 0, stream>>>(xb, Wb, bq, bk, bv, qt, kt, vt, scaling);
  k_attn_mm<<<dim3(16, 32), 256, 0, stream>>>(qt, kt, lgt);
  k_softmax<<<2048, 256, 0, stream>>>(lgt, dist, rel, probs, pbf);
  k_vtrans<<<8192, 256, 0, stream>>>(vt, vtt);
  k_ctx_mm<<<dim3(64, 32), 256, 0, stream>>>(vtt, pbf, ctT);
  k_ctrans<<<2048, 256, 0, stream>>>(ctT, ctb);
  k_oproj_mm<<<2048, 256, 0, stream>>>(ctb, Wb + 196608, bo, out);
}